// Round 2
// baseline (31231.229 us; speedup 1.0000x reference)
//
#include <hip/hip_runtime.h>
#include <hip/hip_cooperative_groups.h>
#include <cstddef>

namespace cg = cooperative_groups;

#define BB 256
#define TT 256
#define UU 512
#define MM 64
#define NT 512
#define APAD 516   // lds A row stride (floats): odd*4 -> distinct bank-quads per row
#define PPAD 520   // k-split partial row stride

// Persistent cooperative kernel, 256 blocks x 512 threads (1 block/CU).
// Phase 1 (block b owns batch b): write_w(t-1) via reg/global GEMV, mem update
//   (mem[b,:,u] in 64 VGPRs of thread u), mean, logits (Wr preloaded in VGPRs),
//   softmax, attended -> ws_att.
// Phase 2 (blocks re-tiled 16x16): C=relu(A@Wt+bt), per-thread 4x4 register
//   tile, split-K 16, ds_read_b128 operands, LDS reduce; -> out + ws_tr.
__global__ __launch_bounds__(NT, 2) void dnc_kernel(
    const float* __restrict__ x,     // [B,T,U]
    const float* __restrict__ mem0,  // [B, M*U]
    const float* __restrict__ Wr,    // [U, M+1]
    const float* __restrict__ br,    // [M+1]
    const float* __restrict__ Wt,    // [U, U]
    const float* __restrict__ bt,    // [U]
    const float* __restrict__ Ww,    // [U, M]
    const float* __restrict__ bw,    // [M]
    float* __restrict__ out,         // [B,T,U]
    float* __restrict__ ws_att,      // [B,U]
    float* __restrict__ ws_tr)       // [B,U]
{
    cg::grid_group grid = cg::this_grid();
    const int b   = blockIdx.x;
    const int tid = threadIdx.x;

    // phase-2 ids: block -> (rt,ct) tile of C[256][512]; thread -> (ks, r4, c4)
    const int rt   = blockIdx.x >> 4;   // 16 rows
    const int ct   = blockIdx.x & 15;   // 32 cols
    const int ks   = tid >> 5;          // 0..15 k-slice
    const int tile = tid & 31;
    const int r4   = tile >> 3;         // rows r4 + 4j, j=0..3
    const int c4   = tile & 7;          // cols c4*4 .. +3

    // phase-1 ids: (cc = k-chunk, jj = output col)
    const int cc = tid >> 6;            // 0..7
    const int jj = tid & 63;            // 0..63

    __shared__ __align__(16) float lds_big[16 * APAD + 128 * 32]; // 49408 B
    float* const Abuf = lds_big;                 // [16][APAD]
    float* const Wbuf = lds_big + 16 * APAD;     // [128][32]
    float* const part = lds_big;                 // [16][PPAD], aliased (post-compute)

    __shared__ __align__(16) float lds_mean[UU];
    __shared__ __align__(16) float lds_tr[UU];
    __shared__ __align__(16) float p1[8 * 72];
    __shared__ __align__(16) float p2[8 * 68];
    __shared__ __align__(16) float lds_rw[68];
    __shared__ __align__(16) float lds_ww[MM];

    // Preload this thread's Wr column slice (fixed across all t)
    float wrReg[64];
#pragma unroll
    for (int k = 0; k < 64; ++k)
        wrReg[k] = Wr[(size_t)(cc * 64 + k) * 65 + jj];

    // register-resident memory column mem[b, 0..63, tid]
    float memc[MM];
#pragma unroll
    for (int m = 0; m < MM; ++m)
        memc[m] = mem0[(size_t)b * (MM * UU) + (size_t)m * UU + tid];

    for (int t = 0; t < TT; ++t) {
        float xv = x[(size_t)b * TT * UU + (size_t)t * UU + tid];

        // ---------------- phase 1 ----------------
        if (t > 0) {
            float trv = ws_tr[b * UU + tid];
            lds_tr[tid] = trv;
            __syncthreads();
            // write_w partial: p = sum_{k in chunk cc} tr[k] * Ww[k][jj]
            float p = 0.f;
#pragma unroll
            for (int q = 0; q < 16; ++q) {
                float4 tv = *(const float4*)&lds_tr[cc * 64 + q * 4];  // broadcast
                p += tv.x * Ww[(size_t)(cc * 64 + q * 4 + 0) * MM + jj];
                p += tv.y * Ww[(size_t)(cc * 64 + q * 4 + 1) * MM + jj];
                p += tv.z * Ww[(size_t)(cc * 64 + q * 4 + 2) * MM + jj];
                p += tv.w * Ww[(size_t)(cc * 64 + q * 4 + 3) * MM + jj];
            }
            p2[cc * 68 + jj] = p;
            __syncthreads();
            if (tid < MM) {
                float s = bw[tid];
#pragma unroll
                for (int c = 0; c < 8; ++c) s += p2[c * 68 + tid];
                lds_ww[tid] = 1.f / (1.f + __expf(-s));
            }
            __syncthreads();
#pragma unroll
            for (int q = 0; q < 16; ++q) {
                float4 wv = *(const float4*)&lds_ww[q * 4];            // broadcast
                memc[q*4+0] = (1.f - wv.x) * memc[q*4+0] + wv.x * trv;
                memc[q*4+1] = (1.f - wv.y) * memc[q*4+1] + wv.y * trv;
                memc[q*4+2] = (1.f - wv.z) * memc[q*4+2] + wv.z * trv;
                memc[q*4+3] = (1.f - wv.w) * memc[q*4+3] + wv.w * trv;
            }
        }

        // mean over M+1 rows
        float colsum = 0.f;
#pragma unroll
        for (int m = 0; m < MM; ++m) colsum += memc[m];
        lds_mean[tid] = (colsum + xv) * (1.f / 65.f);
        __syncthreads();

        // logits partial for col jj over chunk cc (Wr from registers)
        {
            float p = 0.f;
#pragma unroll
            for (int q = 0; q < 16; ++q) {
                float4 mv = *(const float4*)&lds_mean[cc * 64 + q * 4]; // broadcast
                p += mv.x * wrReg[q*4+0] + mv.y * wrReg[q*4+1]
                   + mv.z * wrReg[q*4+2] + mv.w * wrReg[q*4+3];
            }
            p1[cc * 72 + jj] = p;
        }
        if (jj == 0) {  // 65th logit column, one lane per wave
            float p64 = 0.f;
#pragma unroll
            for (int k = 0; k < 64; ++k)
                p64 += lds_mean[cc * 64 + k] * Wr[(size_t)(cc * 64 + k) * 65 + 64];
            p1[cc * 72 + 64] = p64;
        }
        __syncthreads();

        // softmax over 65 on wave 0
        if (tid < 64) {
            float lj = br[tid];
#pragma unroll
            for (int c = 0; c < 8; ++c) lj += p1[c * 72 + tid];
            float l64 = 0.f;
            if (tid == 0) {
                l64 = br[64];
#pragma unroll
                for (int c = 0; c < 8; ++c) l64 += p1[c * 72 + 64];
            }
            float mx = lj;
            if (tid == 0) mx = fmaxf(mx, l64);
#pragma unroll
            for (int o = 32; o >= 1; o >>= 1) mx = fmaxf(mx, __shfl_xor(mx, o, 64));
            float e = __expf(lj - mx);
            float e64 = (tid == 0) ? __expf(l64 - mx) : 0.f;
            float sm = e + e64;
#pragma unroll
            for (int o = 32; o >= 1; o >>= 1) sm += __shfl_xor(sm, o, 64);
            lds_rw[tid] = e / sm;
            if (tid == 0) lds_rw[64] = e64 / sm;
        }
        __syncthreads();

        // attended
        float att = lds_rw[64] * xv;
#pragma unroll
        for (int q = 0; q < 16; ++q) {
            float4 rv = *(const float4*)&lds_rw[q * 4];                 // broadcast
            att += rv.x * memc[q*4+0] + rv.y * memc[q*4+1]
                 + rv.z * memc[q*4+2] + rv.w * memc[q*4+3];
        }
        ws_att[b * UU + tid] = att;

        grid.sync();

        // ---------------- phase 2: C[16x32] tile of relu(A @ Wt + bt) ----------------
        // stage A tile [16][512] -> padded LDS
        {
            const float4* src = (const float4*)(ws_att + (size_t)rt * 16 * UU);
#pragma unroll
            for (int i = 0; i < 4; ++i) {
                int l = tid + i * NT;             // 0..2047 over 16 x 128 float4
                int row = l >> 7, col4 = l & 127;
                *(float4*)&Abuf[row * APAD + col4 * 4] = src[l];
            }
        }

        float acc[4][4];
#pragma unroll
        for (int j = 0; j < 4; ++j) {
#pragma unroll
            for (int i = 0; i < 4; ++i) acc[j][i] = 0.f;
        }

        for (int ch = 0; ch < 4; ++ch) {
            __syncthreads();   // A staged (ch0) / prev chunk reads done
            // stage Wt[ch*128 .. +127][ct*32 .. +31] -> Wbuf[128][32]
#pragma unroll
            for (int i = 0; i < 2; ++i) {
                int l = tid + i * NT;             // 0..1023 over 128 x 8 float4
                int kk = l >> 3, cf = l & 7;
                *(float4*)&Wbuf[kk * 32 + cf * 4] =
                    *(const float4*)(Wt + (size_t)(ch * 128 + kk) * UU + ct * 32 + cf * 4);
            }
            __syncthreads();
            // this thread: k in {ch*128 + ks*8 + 0..7}
#pragma unroll
            for (int s = 0; s < 2; ++s) {
                int kb = ks * 8 + s * 4;
                float4 w0 = *(const float4*)&Wbuf[(kb + 0) * 32 + c4 * 4];
                float4 w1 = *(const float4*)&Wbuf[(kb + 1) * 32 + c4 * 4];
                float4 w2 = *(const float4*)&Wbuf[(kb + 2) * 32 + c4 * 4];
                float4 w3 = *(const float4*)&Wbuf[(kb + 3) * 32 + c4 * 4];
#pragma unroll
                for (int j = 0; j < 4; ++j) {
                    float4 av = *(const float4*)&Abuf[(r4 + 4 * j) * APAD + ch * 128 + kb];
                    acc[j][0] += av.x * w0.x + av.y * w1.x + av.z * w2.x + av.w * w3.x;
                    acc[j][1] += av.x * w0.y + av.y * w1.y + av.z * w2.y + av.w * w3.y;
                    acc[j][2] += av.x * w0.z + av.y * w1.z + av.z * w2.z + av.w * w3.z;
                    acc[j][3] += av.x * w0.w + av.y * w1.w + av.z * w2.w + av.w * w3.w;
                }
            }
        }
        __syncthreads();      // all A/W reads done before aliasing as `part`
#pragma unroll
        for (int j = 0; j < 4; ++j) {
            float4 v = make_float4(acc[j][0], acc[j][1], acc[j][2], acc[j][3]);
            *(float4*)&part[ks * PPAD + (r4 + 4 * j) * 32 + c4 * 4] = v;
        }
        __syncthreads();
        {
            float s = 0.f;
#pragma unroll
            for (int k2 = 0; k2 < 16; ++k2) s += part[k2 * PPAD + tid];
            int row = rt * 16 + (tid >> 5);
            int col = ct * 32 + (tid & 31);
            float tr = fmaxf(s + bt[col], 0.f);
            ws_tr[row * UU + col] = tr;
            out[(size_t)row * TT * UU + (size_t)t * UU + col] = tr;
        }

        grid.sync();
    }
}

extern "C" void kernel_launch(void* const* d_in, const int* in_sizes, int n_in,
                              void* d_out, int out_size, void* d_ws, size_t ws_size,
                              hipStream_t stream) {
    const float* x    = (const float*)d_in[0];
    const float* mem0 = (const float*)d_in[1];
    const float* Wr   = (const float*)d_in[2];
    const float* br   = (const float*)d_in[3];
    const float* Wt   = (const float*)d_in[4];
    const float* bt   = (const float*)d_in[5];
    const float* Ww   = (const float*)d_in[6];
    const float* bw   = (const float*)d_in[7];
    float* out = (float*)d_out;

    float* ws_att = (float*)d_ws;             // [B,U]
    float* ws_tr  = ws_att + BB * UU;         // [B,U]

    void* args[] = {(void*)&x, (void*)&mem0, (void*)&Wr, (void*)&br,
                    (void*)&Wt, (void*)&bt, (void*)&Ww, (void*)&bw,
                    (void*)&out, (void*)&ws_att, (void*)&ws_tr};

    hipLaunchCooperativeKernel((const void*)dnc_kernel, dim3(BB), dim3(NT),
                               args, 0, stream);
}

// Round 3
// 23476.494 us; speedup vs baseline: 1.3303x; 1.3303x over previous
//
#include <hip/hip_runtime.h>
#include <hip/hip_cooperative_groups.h>
#include <cstddef>

namespace cg = cooperative_groups;

#define BB 256
#define TT 256
#define UU 512
#define MM 64
#define NT 512
#define APAD 520   // union A/part row stride (floats); bank start 8*row%32

// Persistent cooperative kernel, 256 blocks x 512 threads (1 block/CU).
// All weights on-chip for the whole run:
//   Wr  -> wrReg[64]/thread (chunk cc=tid>>6, col jj=tid&63) + col-64 in LDS
//   Ww  -> wwReg[64]/thread (same decomposition)
//   Wt  -> per-block column tile [512][32] in LDS, staged once
//   mem -> memc[64]/thread (thread u owns mem[b, :, u])
// Phase 1 (block b = batch b): write_w(t-1), mem update, mean, logits,
//   softmax, attended -> ws_att.   grid.sync
// Phase 2 (block -> (rt=bid&15, ct=bid>>4) tile of C[256][512]):
//   tr = relu(A @ Wt + bt), per-thread 4x4 tile, split-K 16, LDS reduce
//   -> out[b,t,:], ws_tr.          grid.sync
__global__ __launch_bounds__(NT, 2) void dnc_kernel(
    const float* __restrict__ x,     // [B,T,U]
    const float* __restrict__ mem0,  // [B, M*U]
    const float* __restrict__ Wr,    // [U, M+1]
    const float* __restrict__ br,    // [M+1]
    const float* __restrict__ Wt,    // [U, U]
    const float* __restrict__ bt,    // [U]
    const float* __restrict__ Ww,    // [U, M]
    const float* __restrict__ bw,    // [M]
    float* __restrict__ out,         // [B,T,U]
    float* __restrict__ ws_att,      // [B,U]
    float* __restrict__ ws_tr)       // [B,U]
{
    cg::grid_group grid = cg::this_grid();
    const int b   = blockIdx.x;
    const int tid = threadIdx.x;

    // phase-2 ids: same-rt blocks -> same XCD (bid%8 preserved for bid&15)
    const int rt   = blockIdx.x & 15;   // A-row group
    const int ct   = blockIdx.x >> 4;   // Wt column group
    const int ks   = tid >> 5;          // 0..15 k-slice
    const int tile = tid & 31;
    const int r4   = tile >> 3;         // rows r4 + 4j
    const int c4   = tile & 7;          // cols c4*4 .. +3

    // phase-1 ids
    const int cc = tid >> 6;            // k-chunk 0..7
    const int jj = tid & 63;            // output col 0..63

    __shared__ __align__(16) float Wtile[UU * 32];     // 64 KB, persistent
    __shared__ __align__(16) float AP[16 * APAD];      // A tile / k-split partials
    __shared__ __align__(16) float lds_mean[UU];
    __shared__ __align__(16) float lds_tr[UU];
    __shared__ __align__(16) float p1[8 * 72];
    __shared__ __align__(16) float p2[8 * 68];
    __shared__ __align__(16) float lds_rw[72];
    __shared__ __align__(16) float lds_ww[MM];
    __shared__ __align__(16) float pbuf[UU];
    __shared__ __align__(16) float wr64_lds[UU];

    // ---- one-time staging ----
    // Wt column tile: Wt[k][ct*32 + c], k=0..511
#pragma unroll
    for (int i = 0; i < 8; ++i) {
        int l = tid + i * NT;            // 0..4095 over 512 rows x 8 float4
        int k = l >> 3, cf = l & 7;
        *(float4*)&Wtile[k * 32 + cf * 4] =
            *(const float4*)(Wt + (size_t)k * UU + ct * 32 + cf * 4);
    }
    wr64_lds[tid] = Wr[(size_t)tid * 65 + 64];

    float wrReg[64], wwReg[64];
#pragma unroll
    for (int k = 0; k < 64; ++k) {
        wrReg[k] = Wr[(size_t)(cc * 64 + k) * 65 + jj];
        wwReg[k] = Ww[(size_t)(cc * 64 + k) * MM + jj];
    }

    float memc[MM];
#pragma unroll
    for (int m = 0; m < MM; ++m)
        memc[m] = mem0[(size_t)b * (MM * UU) + (size_t)m * UU + tid];

    for (int t = 0; t < TT; ++t) {
        float xv = x[(size_t)b * TT * UU + (size_t)t * UU + tid];

        // ---------------- phase 1 ----------------
        if (t > 0) {
            float trv = ws_tr[b * UU + tid];
            lds_tr[tid] = trv;
            __syncthreads();
            float p = 0.f;
#pragma unroll
            for (int q = 0; q < 16; ++q) {
                float4 tv = *(const float4*)&lds_tr[cc * 64 + q * 4];  // broadcast
                p += tv.x * wwReg[q*4+0] + tv.y * wwReg[q*4+1]
                   + tv.z * wwReg[q*4+2] + tv.w * wwReg[q*4+3];
            }
            p2[cc * 68 + jj] = p;
            __syncthreads();
            if (tid < MM) {
                float s = bw[tid];
#pragma unroll
                for (int c = 0; c < 8; ++c) s += p2[c * 68 + tid];
                lds_ww[tid] = 1.f / (1.f + __expf(-s));
            }
            __syncthreads();
#pragma unroll
            for (int q = 0; q < 16; ++q) {
                float4 wv = *(const float4*)&lds_ww[q * 4];            // broadcast
                memc[q*4+0] = (1.f - wv.x) * memc[q*4+0] + wv.x * trv;
                memc[q*4+1] = (1.f - wv.y) * memc[q*4+1] + wv.y * trv;
                memc[q*4+2] = (1.f - wv.z) * memc[q*4+2] + wv.z * trv;
                memc[q*4+3] = (1.f - wv.w) * memc[q*4+3] + wv.w * trv;
            }
        }

        // mean over M+1 rows
        float colsum = 0.f;
#pragma unroll
        for (int m = 0; m < MM; ++m) colsum += memc[m];
        lds_mean[tid] = (colsum + xv) * (1.f / 65.f);
        __syncthreads();

        // logits partial (cols 0..63) + col-64 products
        {
            float p = 0.f;
#pragma unroll
            for (int q = 0; q < 16; ++q) {
                float4 mv = *(const float4*)&lds_mean[cc * 64 + q * 4]; // broadcast
                p += mv.x * wrReg[q*4+0] + mv.y * wrReg[q*4+1]
                   + mv.z * wrReg[q*4+2] + mv.w * wrReg[q*4+3];
            }
            p1[cc * 72 + jj] = p;
            pbuf[tid] = lds_mean[tid] * wr64_lds[tid];
        }
        __syncthreads();

        // softmax over 65 on wave 0
        if (tid < 64) {
            float lj = br[tid];
#pragma unroll
            for (int c = 0; c < 8; ++c) lj += p1[c * 72 + tid];
            float4 pa = *(const float4*)&pbuf[tid * 8];
            float4 pb = *(const float4*)&pbuf[tid * 8 + 4];
            float s64 = pa.x + pa.y + pa.z + pa.w + pb.x + pb.y + pb.z + pb.w;
#pragma unroll
            for (int o = 32; o >= 1; o >>= 1) s64 += __shfl_xor(s64, o, 64);
            float l64 = s64 + br[64];
            float mx = fmaxf(lj, l64);
#pragma unroll
            for (int o = 32; o >= 1; o >>= 1) mx = fmaxf(mx, __shfl_xor(mx, o, 64));
            float e = __expf(lj - mx);
            float e64 = __expf(l64 - mx);
            float sm = e;
#pragma unroll
            for (int o = 32; o >= 1; o >>= 1) sm += __shfl_xor(sm, o, 64);
            sm += e64;
            lds_rw[tid] = e / sm;
            if (tid == 0) lds_rw[64] = e64 / sm;
        }
        __syncthreads();

        // attended
        float att = lds_rw[64] * xv;
#pragma unroll
        for (int q = 0; q < 16; ++q) {
            float4 rv = *(const float4*)&lds_rw[q * 4];                 // broadcast
            att += rv.x * memc[q*4+0] + rv.y * memc[q*4+1]
                 + rv.z * memc[q*4+2] + rv.w * memc[q*4+3];
        }
        ws_att[b * UU + tid] = att;

        grid.sync();

        // ---------------- phase 2: C[16x32] tile of relu(A @ Wt + bt) ----------------
        {
            const float4* src = (const float4*)(ws_att + (size_t)rt * 16 * UU);
#pragma unroll
            for (int i = 0; i < 4; ++i) {
                int l = tid + i * NT;             // 16 rows x 128 float4
                int row = l >> 7, col4 = l & 127;
                *(float4*)&AP[row * APAD + col4 * 4] = src[l];
            }
        }
        __syncthreads();

        float acc[4][4];
#pragma unroll
        for (int j = 0; j < 4; ++j)
#pragma unroll
            for (int i = 0; i < 4; ++i) acc[j][i] = 0.f;

#pragma unroll
        for (int ch = 0; ch < 4; ++ch) {
#pragma unroll
            for (int s = 0; s < 2; ++s) {
                int kb = ch * 128 + ks * 8 + s * 4;
                float4 w0 = *(const float4*)&Wtile[(kb + 0) * 32 + c4 * 4];
                float4 w1 = *(const float4*)&Wtile[(kb + 1) * 32 + c4 * 4];
                float4 w2 = *(const float4*)&Wtile[(kb + 2) * 32 + c4 * 4];
                float4 w3 = *(const float4*)&Wtile[(kb + 3) * 32 + c4 * 4];
#pragma unroll
                for (int j = 0; j < 4; ++j) {
                    float4 av = *(const float4*)&AP[(r4 + 4 * j) * APAD + kb];
                    acc[j][0] += av.x * w0.x + av.y * w1.x + av.z * w2.x + av.w * w3.x;
                    acc[j][1] += av.x * w0.y + av.y * w1.y + av.z * w2.y + av.w * w3.y;
                    acc[j][2] += av.x * w0.z + av.y * w1.z + av.z * w2.z + av.w * w3.z;
                    acc[j][3] += av.x * w0.w + av.y * w1.w + av.z * w2.w + av.w * w3.w;
                }
            }
        }
        __syncthreads();      // all A reads done before aliasing AP as partials
#pragma unroll
        for (int j = 0; j < 4; ++j) {
            float4 v = make_float4(acc[j][0], acc[j][1], acc[j][2], acc[j][3]);
            *(float4*)&AP[ks * APAD + (r4 + 4 * j) * 32 + c4 * 4] = v;
        }
        __syncthreads();
        {
            float s = 0.f;
#pragma unroll
            for (int k2 = 0; k2 < 16; ++k2) s += AP[k2 * APAD + tid];
            int row = rt * 16 + (tid >> 5);
            int col = ct * 32 + (tid & 31);
            float tr = fmaxf(s + bt[col], 0.f);
            ws_tr[row * UU + col] = tr;
            out[(size_t)row * TT * UU + (size_t)t * UU + col] = tr;
        }

        grid.sync();
    }
}

extern "C" void kernel_launch(void* const* d_in, const int* in_sizes, int n_in,
                              void* d_out, int out_size, void* d_ws, size_t ws_size,
                              hipStream_t stream) {
    const float* x    = (const float*)d_in[0];
    const float* mem0 = (const float*)d_in[1];
    const float* Wr   = (const float*)d_in[2];
    const float* br   = (const float*)d_in[3];
    const float* Wt   = (const float*)d_in[4];
    const float* bt   = (const float*)d_in[5];
    const float* Ww   = (const float*)d_in[6];
    const float* bw   = (const float*)d_in[7];
    float* out = (float*)d_out;

    float* ws_att = (float*)d_ws;             // [B,U]
    float* ws_tr  = ws_att + BB * UU;         // [B,U]

    void* args[] = {(void*)&x, (void*)&mem0, (void*)&Wr, (void*)&br,
                    (void*)&Wt, (void*)&bt, (void*)&Ww, (void*)&bw,
                    (void*)&out, (void*)&ws_att, (void*)&ws_tr};

    hipLaunchCooperativeKernel((const void*)dnc_kernel, dim3(BB), dim3(NT),
                               args, 0, stream);
}

// Round 5
// 17820.448 us; speedup vs baseline: 1.7526x; 1.3174x over previous
//
#include <hip/hip_runtime.h>
#include <hip/hip_cooperative_groups.h>
#include <cstddef>

namespace cg = cooperative_groups;

#define BB 256
#define TT 256
#define UU 512
#define MM 64
#define NT 512
#define APAD 520   // union A/partials row stride (floats)

// Persistent cooperative kernel, 256 blocks x 512 threads (1 block/CU).
// NO register-cached weights (rounds 2-4 showed they spill or kill the
// launch). Wr/Ww are streamed from global each step: lanes read consecutive
// addresses (coalesced) and all blocks read the same lines in the same order
// (L2/L3-shared, ~2.1 MB/step grid-wide compulsory).
//   mem -> memc[64]/thread (thread u owns mem[b, :, u])
//   Wt  -> per-block column tile [512][32] in LDS, staged once
// Phase 1 (block b = batch b): write_w(t-1), mem update, mean, logits,
//   softmax, attended -> ws_att.   grid.sync
// Phase 2 (block -> (rt=bid&15, ct=bid>>4) tile of C[256][512]):
//   relu(A @ Wt + bt), per-thread 4x4 tile, split-K 16, LDS reduce
//   -> out[.,t,.], ws_tr.          grid.sync
__global__ __launch_bounds__(NT, 2) void dnc_kernel(
    const float* __restrict__ x,     // [B,T,U]
    const float* __restrict__ mem0,  // [B, M*U]
    const float* __restrict__ Wr,    // [U, M+1]
    const float* __restrict__ br,    // [M+1]
    const float* __restrict__ Wt,    // [U, U]
    const float* __restrict__ bt,    // [U]
    const float* __restrict__ Ww,    // [U, M]
    const float* __restrict__ bw,    // [M]
    float* __restrict__ out,         // [B,T,U]
    float* __restrict__ ws_att,      // [B,U]
    float* __restrict__ ws_tr)       // [B,U]
{
    cg::grid_group grid = cg::this_grid();
    const int b   = blockIdx.x;
    const int tid = threadIdx.x;       // 0..511

    // phase-2 ids
    const int rt   = blockIdx.x & 15;  // A-row group (same-rt -> same XCD)
    const int ct   = blockIdx.x >> 4;  // Wt column group
    const int ks   = tid >> 5;         // 0..15 k-slice
    const int tile = tid & 31;
    const int r4   = tile >> 3;        // rows r4 + 4j
    const int c4   = tile & 7;         // cols c4*4 .. +3

    // phase-1 ids
    const int cc = tid >> 6;           // k-chunk 0..7 (64 wide)
    const int jj = tid & 63;           // output col 0..63

    __shared__ __align__(16) float Wtile[UU * 32];   // 64 KB, persistent
    __shared__ __align__(16) float AP[16 * APAD];    // A tile / k-split partials
    __shared__ __align__(16) float lds_mean[UU];
    __shared__ __align__(16) float lds_tr[UU];
    __shared__ __align__(16) float p1[8 * 72];
    __shared__ __align__(16) float p2[8 * 68];
    __shared__ __align__(16) float lds_rw[72];
    __shared__ __align__(16) float lds_ww[MM];
    __shared__ __align__(16) float pbuf[UU];
    __shared__ __align__(16) float wr64_lds[UU];

    // ---- one-time staging ----
#pragma unroll
    for (int i = 0; i < 8; ++i) {      // Wt[k][ct*32+c], 4096 float4
        int l = tid + i * NT;
        int k = l >> 3, cf = l & 7;
        *(float4*)&Wtile[k * 32 + cf * 4] =
            *(const float4*)(Wt + (size_t)k * UU + ct * 32 + cf * 4);
    }
    wr64_lds[tid] = Wr[(size_t)tid * 65 + 64];

    float memc[MM];
#pragma unroll
    for (int m = 0; m < MM; ++m)
        memc[m] = mem0[(size_t)b * (MM * UU) + (size_t)m * UU + tid];

    const float brv  = (tid < 64) ? br[tid] : 0.f;
    const float br64 = br[64];
    const float bwv  = (tid < 64) ? bw[tid] : 0.f;
    const float btv  = bt[ct * 32 + (tid & 31)];

    // x prefetch for t=0 (registers only)
    float xv = x[(size_t)b * TT * UU + tid];

    for (int t = 0; t < TT; ++t) {
        // ---------------- phase 1 ----------------
        if (t > 0) {
            float trv = ws_tr[b * UU + tid];
            lds_tr[tid] = trv;
            __syncthreads();
            // write_w partial: p = sum_{k in chunk cc} tr[k] * Ww[k][jj]
            {
                float p = 0.f;
                const float* wwp = Ww + (size_t)(cc * 64) * MM + jj;
#pragma unroll 16
                for (int k = 0; k < 64; ++k)
                    p += lds_tr[cc * 64 + k] * wwp[(size_t)k * MM];
                p2[cc * 68 + jj] = p;
            }
            __syncthreads();
            if (tid < MM) {
                float s = bwv;
#pragma unroll
                for (int c = 0; c < 8; ++c) s += p2[c * 68 + tid];
                lds_ww[tid] = 1.f / (1.f + __expf(-s));
            }
            __syncthreads();
#pragma unroll
            for (int q = 0; q < 16; ++q) {
                float4 wv = *(const float4*)&lds_ww[q * 4];            // broadcast
                memc[q*4+0] = (1.f - wv.x) * memc[q*4+0] + wv.x * trv;
                memc[q*4+1] = (1.f - wv.y) * memc[q*4+1] + wv.y * trv;
                memc[q*4+2] = (1.f - wv.z) * memc[q*4+2] + wv.z * trv;
                memc[q*4+3] = (1.f - wv.w) * memc[q*4+3] + wv.w * trv;
            }
        }

        // mean over M+1 rows
        float colsum = 0.f;
#pragma unroll
        for (int m = 0; m < MM; ++m) colsum += memc[m];
        float meanv = (colsum + xv) * (1.f / 65.f);
        lds_mean[tid] = meanv;
        pbuf[tid] = meanv * wr64_lds[tid];
        __syncthreads();

        // logits partial (cols 0..63), Wr streamed from global (coalesced,
        // same lines for every block -> L2/L3 hits)
        {
            float p = 0.f;
            const float* wrp = Wr + (size_t)(cc * 64) * 65 + jj;
#pragma unroll 16
            for (int k = 0; k < 64; ++k)
                p += lds_mean[cc * 64 + k] * wrp[(size_t)k * 65];
            p1[cc * 72 + jj] = p;
        }
        __syncthreads();

        // softmax over 65 on wave 0
        if (tid < 64) {
            float lj = brv;
#pragma unroll
            for (int c = 0; c < 8; ++c) lj += p1[c * 72 + tid];
            float4 pa = *(const float4*)&pbuf[tid * 8];
            float4 pb = *(const float4*)&pbuf[tid * 8 + 4];
            float s64 = pa.x + pa.y + pa.z + pa.w + pb.x + pb.y + pb.z + pb.w;
#pragma unroll
            for (int o = 32; o >= 1; o >>= 1) s64 += __shfl_xor(s64, o, 64);
            float l64 = s64 + br64;
            float mx = fmaxf(lj, l64);
#pragma unroll
            for (int o = 32; o >= 1; o >>= 1) mx = fmaxf(mx, __shfl_xor(mx, o, 64));
            float e = __expf(lj - mx);
            float e64 = __expf(l64 - mx);
            float sm = e;
#pragma unroll
            for (int o = 32; o >= 1; o >>= 1) sm += __shfl_xor(sm, o, 64);
            sm += e64;
            lds_rw[tid] = e / sm;
            if (tid == 0) lds_rw[64] = e64 / sm;
        }
        __syncthreads();

        // attended
        float att = lds_rw[64] * xv;
#pragma unroll
        for (int q = 0; q < 16; ++q) {
            float4 rv = *(const float4*)&lds_rw[q * 4];                 // broadcast
            att += rv.x * memc[q*4+0] + rv.y * memc[q*4+1]
                 + rv.z * memc[q*4+2] + rv.w * memc[q*4+3];
        }
        ws_att[b * UU + tid] = att;

        grid.sync();

        // ---------------- phase 2: C[16x32] tile of relu(A @ Wt + bt) ----------------
        {
            const float4* src = (const float4*)(ws_att + (size_t)rt * 16 * UU);
#pragma unroll
            for (int i = 0; i < 4; ++i) {
                int l = tid + i * NT;             // 16 rows x 128 float4
                int row = l >> 7, col4 = l & 127;
                *(float4*)&AP[row * APAD + col4 * 4] = src[l];
            }
        }
        __syncthreads();

        float acc[4][4];
#pragma unroll
        for (int j = 0; j < 4; ++j)
#pragma unroll
            for (int i = 0; i < 4; ++i) acc[j][i] = 0.f;

#pragma unroll
        for (int ch = 0; ch < 4; ++ch) {
#pragma unroll
            for (int s = 0; s < 2; ++s) {
                int kb = ch * 128 + ks * 8 + s * 4;
                float4 w0 = *(const float4*)&Wtile[(kb + 0) * 32 + c4 * 4];
                float4 w1 = *(const float4*)&Wtile[(kb + 1) * 32 + c4 * 4];
                float4 w2 = *(const float4*)&Wtile[(kb + 2) * 32 + c4 * 4];
                float4 w3 = *(const float4*)&Wtile[(kb + 3) * 32 + c4 * 4];
#pragma unroll
                for (int j = 0; j < 4; ++j) {
                    float4 av = *(const float4*)&AP[(r4 + 4 * j) * APAD + kb];
                    acc[j][0] += av.x * w0.x + av.y * w1.x + av.z * w2.x + av.w * w3.x;
                    acc[j][1] += av.x * w0.y + av.y * w1.y + av.z * w2.y + av.w * w3.y;
                    acc[j][2] += av.x * w0.z + av.y * w1.z + av.z * w2.z + av.w * w3.z;
                    acc[j][3] += av.x * w0.w + av.y * w1.w + av.z * w2.w + av.w * w3.w;
                }
            }
        }
        __syncthreads();      // all A reads done before aliasing AP as partials
#pragma unroll
        for (int j = 0; j < 4; ++j) {
            float4 v = make_float4(acc[j][0], acc[j][1], acc[j][2], acc[j][3]);
            *(float4*)&AP[ks * APAD + (r4 + 4 * j) * 32 + c4 * 4] = v;
        }
        __syncthreads();
        {
            float s = 0.f;
#pragma unroll
            for (int k2 = 0; k2 < 16; ++k2) s += AP[k2 * APAD + tid];
            int row = rt * 16 + (tid >> 5);
            int col = ct * 32 + (tid & 31);
            float tr = fmaxf(s + btv, 0.f);
            ws_tr[row * UU + col] = tr;
            out[(size_t)row * TT * UU + (size_t)t * UU + col] = tr;
        }

        // prefetch x for next step (registers only, hides post-sync latency)
        {
            int tn = (t + 1 < TT) ? t + 1 : t;
            xv = x[(size_t)b * TT * UU + (size_t)tn * UU + tid];
        }

        grid.sync();
    }
}

extern "C" void kernel_launch(void* const* d_in, const int* in_sizes, int n_in,
                              void* d_out, int out_size, void* d_ws, size_t ws_size,
                              hipStream_t stream) {
    const float* x    = (const float*)d_in[0];
    const float* mem0 = (const float*)d_in[1];
    const float* Wr   = (const float*)d_in[2];
    const float* br   = (const float*)d_in[3];
    const float* Wt   = (const float*)d_in[4];
    const float* bt   = (const float*)d_in[5];
    const float* Ww   = (const float*)d_in[6];
    const float* bw   = (const float*)d_in[7];
    float* out = (float*)d_out;

    float* ws_att = (float*)d_ws;             // [B,U]
    float* ws_tr  = ws_att + BB * UU;         // [B,U]

    void* args[] = {(void*)&x, (void*)&mem0, (void*)&Wr, (void*)&br,
                    (void*)&Wt, (void*)&bt, (void*)&Ww, (void*)&bw,
                    (void*)&out, (void*)&ws_att, (void*)&ws_tr};

    hipLaunchCooperativeKernel((const void*)dnc_kernel, dim3(BB), dim3(NT),
                               args, 0, stream);
}

// Round 6
// 6811.895 us; speedup vs baseline: 4.5848x; 2.6161x over previous
//
#include <hip/hip_runtime.h>
#include <cstddef>

#define BB 256
#define TT 256
#define UU 512
#define MM 64
#define NT 512

// One block per batch row, fully independent — NO grid synchronization.
// Block b runs the whole T=256 recurrence for batch b:
//   mem[b,:,u]   -> memc[64] registers of thread u
//   transformed  -> tr_lds (never leaves the CU)
//   Wr/Ww/Wt     -> read from global each step; all 256 blocks read the same
//                   1.26 MB in the same order -> L2-resident per XCD (no
//                   grid fences to invalidate it).
// Per step: write-GEMV(Ww) -> sigmoid -> mem update -> mean -> read-GEMV(Wr)
//   -> softmax (wave 0) -> attended -> Wt-GEMV (float4, split-K over 8 waves,
//   LDS reduce) -> relu -> out.
__global__ __launch_bounds__(NT, 2) void dnc_kernel(
    const float* __restrict__ x,     // [B,T,U]
    const float* __restrict__ mem0,  // [B, M*U]
    const float* __restrict__ Wr,    // [U, M+1]
    const float* __restrict__ br,    // [M+1]
    const float* __restrict__ Wt,    // [U, U]
    const float* __restrict__ bt,    // [U]
    const float* __restrict__ Ww,    // [U, M]
    const float* __restrict__ bw,    // [M]
    float* __restrict__ out)         // [B,T,U]
{
    const int b   = blockIdx.x;
    const int tid = threadIdx.x;   // 0..511
    const int kc  = tid >> 6;      // wave id == k-chunk 0..7 (64 k each)
    const int jj  = tid & 63;      // lane / output col within group

    __shared__ __align__(16) float att_lds[UU];
    __shared__ __align__(16) float tr_lds[UU];
    __shared__ __align__(16) float mean_lds[UU];
    __shared__ __align__(16) float pbuf[UU];
    __shared__ __align__(16) float pWt[8][UU];   // Wt-GEMV k-split partials
    __shared__ __align__(16) float p1[8 * 72];   // read-GEMV partials
    __shared__ __align__(16) float p2[8 * 68];   // write-GEMV partials
    __shared__ __align__(16) float lds_rw[72];
    __shared__ __align__(16) float lds_ww[MM];

    // mem[b, m, tid] in registers
    float memc[MM];
#pragma unroll
    for (int m = 0; m < MM; ++m)
        memc[m] = mem0[(size_t)b * (MM * UU) + (size_t)m * UU + tid];

    const float brv  = (tid < 64) ? br[tid] : 0.f;
    const float br64 = br[64];
    const float bwv  = (tid < 64) ? bw[tid] : 0.f;
    const float btv  = bt[tid];
    const float wr64 = Wr[(size_t)tid * 65 + 64];   // col-64 of Wr, row tid

    const float4* Wt4 = (const float4*)Wt;          // [512][128] float4

    float xv = x[(size_t)b * TT * UU + tid];        // x[b,0,tid]

    for (int t = 0; t < TT; ++t) {
        // ---- write weights of t-1, mem update ----
        if (t > 0) {
            {
                float p = 0.f;
                const float* wwp = Ww + (size_t)(kc * 64) * MM + jj;
#pragma unroll 16
                for (int k = 0; k < 64; ++k)
                    p += tr_lds[kc * 64 + k] * wwp[(size_t)k * MM];
                p2[kc * 68 + jj] = p;
            }
            __syncthreads();
            if (tid < MM) {
                float s = bwv;
#pragma unroll
                for (int c = 0; c < 8; ++c) s += p2[c * 68 + tid];
                lds_ww[tid] = 1.f / (1.f + __expf(-s));
            }
            __syncthreads();
            float trv = tr_lds[tid];
#pragma unroll
            for (int q = 0; q < 16; ++q) {
                float4 wv = *(const float4*)&lds_ww[q * 4];   // broadcast
                memc[q*4+0] = (1.f - wv.x) * memc[q*4+0] + wv.x * trv;
                memc[q*4+1] = (1.f - wv.y) * memc[q*4+1] + wv.y * trv;
                memc[q*4+2] = (1.f - wv.z) * memc[q*4+2] + wv.z * trv;
                memc[q*4+3] = (1.f - wv.w) * memc[q*4+3] + wv.w * trv;
            }
        }

        // ---- mean over M+1 rows ----
        float colsum = 0.f;
#pragma unroll
        for (int m = 0; m < MM; ++m) colsum += memc[m];
        float meanv = (colsum + xv) * (1.f / 65.f);
        mean_lds[tid] = meanv;
        pbuf[tid] = meanv * wr64;
        __syncthreads();

        // ---- read-GEMV: logits partials (cols 0..63) ----
        {
            float p = 0.f;
            const float* wrp = Wr + (size_t)(kc * 64) * 65 + jj;
#pragma unroll 16
            for (int k = 0; k < 64; ++k)
                p += mean_lds[kc * 64 + k] * wrp[(size_t)k * 65];
            p1[kc * 72 + jj] = p;
        }
        __syncthreads();

        // ---- softmax over 65 on wave 0 ----
        if (tid < 64) {
            float lj = brv;
#pragma unroll
            for (int c = 0; c < 8; ++c) lj += p1[c * 72 + tid];
            float4 pa = *(const float4*)&pbuf[tid * 8];
            float4 pb = *(const float4*)&pbuf[tid * 8 + 4];
            float s64 = pa.x + pa.y + pa.z + pa.w + pb.x + pb.y + pb.z + pb.w;
#pragma unroll
            for (int o = 32; o >= 1; o >>= 1) s64 += __shfl_xor(s64, o, 64);
            float l64 = s64 + br64;
            float mx = fmaxf(lj, l64);
#pragma unroll
            for (int o = 32; o >= 1; o >>= 1) mx = fmaxf(mx, __shfl_xor(mx, o, 64));
            float e = __expf(lj - mx);
            float e64 = __expf(l64 - mx);
            float sm = e;
#pragma unroll
            for (int o = 32; o >= 1; o >>= 1) sm += __shfl_xor(sm, o, 64);
            sm += e64;
            lds_rw[tid] = e / sm;
            if (tid == 0) lds_rw[64] = e64 / sm;
        }
        __syncthreads();

        // ---- attended ----
        float att = lds_rw[64] * xv;
#pragma unroll
        for (int q = 0; q < 16; ++q) {
            float4 rv = *(const float4*)&lds_rw[q * 4];       // broadcast
            att += rv.x * memc[q*4+0] + rv.y * memc[q*4+1]
                 + rv.z * memc[q*4+2] + rv.w * memc[q*4+3];
        }
        att_lds[tid] = att;
        __syncthreads();

        // ---- Wt-GEMV: tr[j] = relu(sum_k att[k] Wt[k,j] + bt[j]) ----
        // wave kc owns k in [kc*64, kc*64+64); lane jj accumulates cols
        // jj*4..+3 and 256+jj*4..+3 via float4 loads (coalesced 1KB/wave/k).
        {
            float4 a0 = make_float4(0.f, 0.f, 0.f, 0.f);
            float4 a1 = make_float4(0.f, 0.f, 0.f, 0.f);
#pragma unroll 8
            for (int k = 0; k < 64; ++k) {
                float a = att_lds[kc * 64 + k];               // broadcast
                float4 w0 = Wt4[(size_t)(kc * 64 + k) * 128 + jj];
                float4 w1 = Wt4[(size_t)(kc * 64 + k) * 128 + 64 + jj];
                a0.x += a * w0.x; a0.y += a * w0.y;
                a0.z += a * w0.z; a0.w += a * w0.w;
                a1.x += a * w1.x; a1.y += a * w1.y;
                a1.z += a * w1.z; a1.w += a * w1.w;
            }
            *(float4*)&pWt[kc][jj * 4]       = a0;
            *(float4*)&pWt[kc][256 + jj * 4] = a1;
        }
        __syncthreads();
        {
            float s = 0.f;
#pragma unroll
            for (int c = 0; c < 8; ++c) s += pWt[c][tid];     // conflict-free
            float tr = fmaxf(s + btv, 0.f);
            tr_lds[tid] = tr;
            out[(size_t)b * TT * UU + (size_t)t * UU + tid] = tr;
        }

        // prefetch next x (register only)
        {
            int tn = (t + 1 < TT) ? t + 1 : t;
            xv = x[(size_t)b * TT * UU + (size_t)tn * UU + tid];
        }
        __syncthreads();   // tr_lds visible for next step's write-GEMV
    }
}

extern "C" void kernel_launch(void* const* d_in, const int* in_sizes, int n_in,
                              void* d_out, int out_size, void* d_ws, size_t ws_size,
                              hipStream_t stream) {
    const float* x    = (const float*)d_in[0];
    const float* mem0 = (const float*)d_in[1];
    const float* Wr   = (const float*)d_in[2];
    const float* br   = (const float*)d_in[3];
    const float* Wt   = (const float*)d_in[4];
    const float* bt   = (const float*)d_in[5];
    const float* Ww   = (const float*)d_in[6];
    const float* bw   = (const float*)d_in[7];
    float* out = (float*)d_out;

    dnc_kernel<<<dim3(BB), dim3(NT), 0, stream>>>(
        x, mem0, Wr, br, Wt, bt, Ww, bw, out);
}

// Round 7
// 3537.486 us; speedup vs baseline: 8.8287x; 1.9256x over previous
//
#include <hip/hip_runtime.h>
#include <cstddef>

#define BB 256
#define TT 256
#define UU 512
#define MM 64
#define NT 1024
#define NBLK 128   // 2 batches per block

// One block per PAIR of batch rows (128 blocks x 1024 threads), no grid sync.
// Each weight line read from L2 feeds both batches (GEMV -> 2-row GEMM):
// halves per-XCD L2 traffic AND doubles waves/CU for latency hiding vs r6.
//   mem[bb,:,ut] -> memc[64] registers of thread (hb,ut)
//   all weights stream from global; 16 blocks/XCD read the same 1.26 MB/step
//   in the same order -> L2-resident.
// Per step: write-GEMM(Ww) -> sigmoid -> mem update -> mean -> read-GEMM(Wr)
//   -> softmax (waves 0/1, one per batch) -> attended -> Wt-GEMM (float4,
//   split-K over 16 waves, LDS reduce) -> relu -> out.
__global__ __launch_bounds__(NT, 1) void dnc_kernel(
    const float* __restrict__ x,     // [B,T,U]
    const float* __restrict__ mem0,  // [B, M*U]
    const float* __restrict__ Wr,    // [U, M+1]
    const float* __restrict__ br,    // [M+1]
    const float* __restrict__ Wt,    // [U, U]
    const float* __restrict__ bt,    // [U]
    const float* __restrict__ Ww,    // [U, M]
    const float* __restrict__ bw,    // [M]
    float* __restrict__ out)         // [B,T,U]
{
    const int tid = threadIdx.x;           // 0..1023
    const int hb  = tid >> 9;              // batch half 0/1 (wave-uniform)
    const int ut  = tid & 511;             // owned column
    const int bb  = (blockIdx.x << 1) + hb;
    const int kc  = tid >> 6;              // wave id 0..15 = k-chunk (32 wide)
    const int jj  = tid & 63;              // lane

    __shared__ __align__(16) float att_lds[2][UU];
    __shared__ __align__(16) float tr_lds[2][UU];
    __shared__ __align__(16) float mean_lds[2][UU];
    __shared__ __align__(16) float pbuf[2][UU];
    __shared__ __align__(16) float pWt[16][2][UU];   // 64 KB k-split partials
    __shared__ __align__(16) float p1[16][2][72];
    __shared__ __align__(16) float p2[16][2][68];
    __shared__ __align__(16) float lds_rw[2][72];
    __shared__ __align__(16) float lds_ww[2][MM];

    // mem[bb, m, ut] in registers
    float memc[MM];
#pragma unroll
    for (int m = 0; m < MM; ++m)
        memc[m] = mem0[(size_t)bb * (MM * UU) + (size_t)m * UU + ut];

    const float btv  = bt[ut];
    const float wr64 = Wr[(size_t)ut * 65 + 64];
    const float bw_j = bw[jj];
    const float br_j = br[jj];
    const float br64 = br[64];

    const float4* Wt4 = (const float4*)Wt;   // [512][128] float4

    float xv = x[(size_t)bb * TT * UU + ut];  // x[bb,0,ut]

    for (int t = 0; t < TT; ++t) {
        // ---- write weights of t-1 (2-row GEMM on Ww), mem update ----
        if (t > 0) {
            {
                float pa = 0.f, pb = 0.f;
                const float* wwp = Ww + (size_t)(kc * 32) * MM + jj;
#pragma unroll 8
                for (int k = 0; k < 32; ++k) {
                    float w = wwp[(size_t)k * MM];        // coalesced, L2-hit
                    pa += tr_lds[0][kc * 32 + k] * w;     // LDS broadcast
                    pb += tr_lds[1][kc * 32 + k] * w;
                }
                p2[kc][0][jj] = pa;
                p2[kc][1][jj] = pb;
            }
            __syncthreads();
            if (tid < 128) {
                int wb = tid >> 6;
                float s = bw_j;
#pragma unroll
                for (int q = 0; q < 16; ++q) s += p2[q][wb][jj];
                lds_ww[wb][jj] = 1.f / (1.f + __expf(-s));
            }
            __syncthreads();
            float trv = tr_lds[hb][ut];
#pragma unroll
            for (int q = 0; q < 16; ++q) {
                float4 wv = *(const float4*)&lds_ww[hb][q * 4];  // broadcast
                memc[q*4+0] = (1.f - wv.x) * memc[q*4+0] + wv.x * trv;
                memc[q*4+1] = (1.f - wv.y) * memc[q*4+1] + wv.y * trv;
                memc[q*4+2] = (1.f - wv.z) * memc[q*4+2] + wv.z * trv;
                memc[q*4+3] = (1.f - wv.w) * memc[q*4+3] + wv.w * trv;
            }
        }

        // ---- mean over M+1 rows ----
        float colsum = 0.f;
#pragma unroll
        for (int m = 0; m < MM; ++m) colsum += memc[m];
        float meanv = (colsum + xv) * (1.f / 65.f);
        mean_lds[hb][ut] = meanv;
        pbuf[hb][ut] = meanv * wr64;
        __syncthreads();

        // ---- read-GEMM: logits partials (cols 0..63) ----
        {
            float pa = 0.f, pb = 0.f;
            const float* wrp = Wr + (size_t)(kc * 32) * 65 + jj;
#pragma unroll 8
            for (int k = 0; k < 32; ++k) {
                float w = wrp[(size_t)k * 65];            // coalesced, L2-hit
                pa += mean_lds[0][kc * 32 + k] * w;
                pb += mean_lds[1][kc * 32 + k] * w;
            }
            p1[kc][0][jj] = pa;
            p1[kc][1][jj] = pb;
        }
        __syncthreads();

        // ---- softmax over 65: wave 0 -> batch 0, wave 1 -> batch 1 ----
        if (tid < 128) {
            int wb = tid >> 6;
            float lj = br_j;
#pragma unroll
            for (int q = 0; q < 16; ++q) lj += p1[q][wb][jj];
            float4 pa4 = *(const float4*)&pbuf[wb][jj * 8];
            float4 pb4 = *(const float4*)&pbuf[wb][jj * 8 + 4];
            float s64 = pa4.x + pa4.y + pa4.z + pa4.w
                      + pb4.x + pb4.y + pb4.z + pb4.w;
#pragma unroll
            for (int o = 32; o >= 1; o >>= 1) s64 += __shfl_xor(s64, o, 64);
            float l64 = s64 + br64;
            float mx = fmaxf(lj, l64);
#pragma unroll
            for (int o = 32; o >= 1; o >>= 1) mx = fmaxf(mx, __shfl_xor(mx, o, 64));
            float e = __expf(lj - mx);
            float e64 = __expf(l64 - mx);
            float sm = e;
#pragma unroll
            for (int o = 32; o >= 1; o >>= 1) sm += __shfl_xor(sm, o, 64);
            sm += e64;
            lds_rw[wb][jj] = e / sm;
            if (jj == 0) lds_rw[wb][64] = e64 / sm;
        }
        __syncthreads();

        // ---- attended ----
        float att = lds_rw[hb][64] * xv;
#pragma unroll
        for (int q = 0; q < 16; ++q) {
            float4 rv = *(const float4*)&lds_rw[hb][q * 4];  // broadcast
            att += rv.x * memc[q*4+0] + rv.y * memc[q*4+1]
                 + rv.z * memc[q*4+2] + rv.w * memc[q*4+3];
        }
        att_lds[hb][ut] = att;
        __syncthreads();

        // ---- Wt 2-row GEMM: wave kc owns k in [kc*32, kc*32+32) ----
        // lane jj: col blocks jj*4 and 256+jj*4, both batches (4 f4 accs).
        {
            float4 a00 = make_float4(0.f,0.f,0.f,0.f);
            float4 a01 = make_float4(0.f,0.f,0.f,0.f);
            float4 a10 = make_float4(0.f,0.f,0.f,0.f);
            float4 a11 = make_float4(0.f,0.f,0.f,0.f);
            const float4* wp = Wt4 + (size_t)(kc * 32) * 128 + jj;
#pragma unroll 2
            for (int k = 0; k < 32; ++k) {
                float4 w0 = wp[(size_t)k * 128];          // coalesced 1KB/wave
                float4 w1 = wp[(size_t)k * 128 + 64];
                float a0 = att_lds[0][kc * 32 + k];       // broadcast
                float a1 = att_lds[1][kc * 32 + k];
                a00.x += a0 * w0.x; a00.y += a0 * w0.y;
                a00.z += a0 * w0.z; a00.w += a0 * w0.w;
                a01.x += a0 * w1.x; a01.y += a0 * w1.y;
                a01.z += a0 * w1.z; a01.w += a0 * w1.w;
                a10.x += a1 * w0.x; a10.y += a1 * w0.y;
                a10.z += a1 * w0.z; a10.w += a1 * w0.w;
                a11.x += a1 * w1.x; a11.y += a1 * w1.y;
                a11.z += a1 * w1.z; a11.w += a1 * w1.w;
            }
            *(float4*)&pWt[kc][0][jj * 4]       = a00;
            *(float4*)&pWt[kc][0][256 + jj * 4] = a01;
            *(float4*)&pWt[kc][1][jj * 4]       = a10;
            *(float4*)&pWt[kc][1][256 + jj * 4] = a11;
        }
        __syncthreads();

        // ---- reduce 16 partials, relu, store ----
        {
            float s = 0.f;
#pragma unroll
            for (int q = 0; q < 16; ++q) s += pWt[q][hb][ut];
            float tr = fmaxf(s + btv, 0.f);
            tr_lds[hb][ut] = tr;
            out[(size_t)bb * TT * UU + (size_t)t * UU + ut] = tr;
        }

        // prefetch next x (register only)
        {
            int tn = (t + 1 < TT) ? t + 1 : t;
            xv = x[(size_t)bb * TT * UU + (size_t)tn * UU + ut];
        }
        __syncthreads();   // tr_lds ready for next step's write-GEMM
    }
}

extern "C" void kernel_launch(void* const* d_in, const int* in_sizes, int n_in,
                              void* d_out, int out_size, void* d_ws, size_t ws_size,
                              hipStream_t stream) {
    const float* x    = (const float*)d_in[0];
    const float* mem0 = (const float*)d_in[1];
    const float* Wr   = (const float*)d_in[2];
    const float* br   = (const float*)d_in[3];
    const float* Wt   = (const float*)d_in[4];
    const float* bt   = (const float*)d_in[5];
    const float* Ww   = (const float*)d_in[6];
    const float* bw   = (const float*)d_in[7];
    float* out = (float*)d_out;

    dnc_kernel<<<dim3(NBLK), dim3(NT), 0, stream>>>(
        x, mem0, Wr, br, Wt, bt, Ww, bw, out);
}

// Round 8
// 3101.067 us; speedup vs baseline: 10.0711x; 1.1407x over previous
//
#include <hip/hip_runtime.h>
#include <cstddef>

#define BB 256
#define TT 256
#define UU 512
#define MM 64
#define NT 1024
#define NBLK 128   // 2 batches per block

typedef _Float16 half8 __attribute__((ext_vector_type(8)));

#define NWT (UU * UU)       // 262144
#define NWR (UU * 65)       // 33280
#define NWW (UU * MM)       // 32768

// One-time (per call) fp32 -> fp16 weight conversion into d_ws.
__global__ void cvt_kernel(const float* __restrict__ Wt,
                           const float* __restrict__ Wr,
                           const float* __restrict__ Ww,
                           _Float16* __restrict__ dst) {
    int i = blockIdx.x * blockDim.x + threadIdx.x;
    int n = NWT + NWR + NWW;
    for (; i < n; i += gridDim.x * blockDim.x) {
        float v;
        if (i < NWT)            v = Wt[i];
        else if (i < NWT + NWR) v = Wr[i - NWT];
        else                    v = Ww[i - NWT - NWR];
        dst[i] = (_Float16)v;
    }
}

// One block per PAIR of batch rows (128 blocks x 1024 threads), no grid sync.
// Same topology as round 7; all weight streams are fp16 (half the bytes
// through the per-CU vector path, which is the measured floor), fp32 math.
__global__ __launch_bounds__(NT, 1) void dnc_kernel(
    const float* __restrict__ x,      // [B,T,U]
    const float* __restrict__ mem0,   // [B, M*U]
    const float* __restrict__ Wr,     // [U, M+1]  (fp32, for col-64 only)
    const float* __restrict__ br,     // [M+1]
    const float* __restrict__ bt,     // [U]
    const float* __restrict__ bw,     // [M]
    const _Float16* __restrict__ Wt16,  // [U][U]
    const _Float16* __restrict__ Wr16,  // [U][65]
    const _Float16* __restrict__ Ww16,  // [U][M]
    float* __restrict__ out)          // [B,T,U]
{
    const int tid = threadIdx.x;           // 0..1023
    const int hb  = tid >> 9;              // batch half 0/1 (wave-uniform)
    const int ut  = tid & 511;             // owned column
    const int bb  = (blockIdx.x << 1) + hb;
    const int kc  = tid >> 6;              // wave id 0..15 = k-chunk (32 wide)
    const int jj  = tid & 63;              // lane

    __shared__ __align__(16) float att_lds[2][UU];
    __shared__ __align__(16) float tr_lds[2][UU];
    __shared__ __align__(16) float mean_lds[2][UU];
    __shared__ __align__(16) float pbuf[2][UU];
    __shared__ __align__(16) float pWt[16][2][UU];   // 64 KB k-split partials
    __shared__ __align__(16) float p1[16][2][72];
    __shared__ __align__(16) float p2[16][2][68];
    __shared__ __align__(16) float lds_rw[2][72];
    __shared__ __align__(16) float lds_ww[2][MM];

    // mem[bb, m, ut] in registers
    float memc[MM];
#pragma unroll
    for (int m = 0; m < MM; ++m)
        memc[m] = mem0[(size_t)bb * (MM * UU) + (size_t)m * UU + ut];

    const float btv  = bt[ut];
    const float wr64 = Wr[(size_t)ut * 65 + 64];
    const float bw_j = bw[jj];
    const float br_j = br[jj];
    const float br64 = br[64];

    const half8* Wt8 = (const half8*)Wt16;   // [512][64] half8

    float xv = x[(size_t)bb * TT * UU + ut];  // x[bb,0,ut]

    for (int t = 0; t < TT; ++t) {
        // ---- write weights of t-1 (2-row GEMM on Ww16), mem update ----
        if (t > 0) {
            {
                float pa = 0.f, pb = 0.f;
                const _Float16* wwp = Ww16 + (size_t)(kc * 32) * MM + jj;
#pragma unroll 8
                for (int k = 0; k < 32; ++k) {
                    float w = (float)wwp[(size_t)k * MM];   // coalesced, L2-hit
                    pa += tr_lds[0][kc * 32 + k] * w;       // LDS broadcast
                    pb += tr_lds[1][kc * 32 + k] * w;
                }
                p2[kc][0][jj] = pa;
                p2[kc][1][jj] = pb;
            }
            __syncthreads();
            if (tid < 128) {
                int wb = tid >> 6;
                float s = bw_j;
#pragma unroll
                for (int q = 0; q < 16; ++q) s += p2[q][wb][jj];
                lds_ww[wb][jj] = 1.f / (1.f + __expf(-s));
            }
            __syncthreads();
            float trv = tr_lds[hb][ut];
#pragma unroll
            for (int q = 0; q < 16; ++q) {
                float4 wv = *(const float4*)&lds_ww[hb][q * 4];  // broadcast
                memc[q*4+0] = (1.f - wv.x) * memc[q*4+0] + wv.x * trv;
                memc[q*4+1] = (1.f - wv.y) * memc[q*4+1] + wv.y * trv;
                memc[q*4+2] = (1.f - wv.z) * memc[q*4+2] + wv.z * trv;
                memc[q*4+3] = (1.f - wv.w) * memc[q*4+3] + wv.w * trv;
            }
        }

        // ---- mean over M+1 rows ----
        float colsum = 0.f;
#pragma unroll
        for (int m = 0; m < MM; ++m) colsum += memc[m];
        float meanv = (colsum + xv) * (1.f / 65.f);
        mean_lds[hb][ut] = meanv;
        pbuf[hb][ut] = meanv * wr64;
        __syncthreads();

        // ---- read-GEMM: logits partials (cols 0..63) ----
        {
            float pa = 0.f, pb = 0.f;
            const _Float16* wrp = Wr16 + (size_t)(kc * 32) * 65 + jj;
#pragma unroll 8
            for (int k = 0; k < 32; ++k) {
                float w = (float)wrp[(size_t)k * 65];       // coalesced, L2-hit
                pa += mean_lds[0][kc * 32 + k] * w;
                pb += mean_lds[1][kc * 32 + k] * w;
            }
            p1[kc][0][jj] = pa;
            p1[kc][1][jj] = pb;
        }
        __syncthreads();

        // ---- softmax over 65: wave 0 -> batch 0, wave 1 -> batch 1 ----
        if (tid < 128) {
            int wb = tid >> 6;
            float lj = br_j;
#pragma unroll
            for (int q = 0; q < 16; ++q) lj += p1[q][wb][jj];
            float4 pa4 = *(const float4*)&pbuf[wb][jj * 8];
            float4 pb4 = *(const float4*)&pbuf[wb][jj * 8 + 4];
            float s64 = pa4.x + pa4.y + pa4.z + pa4.w
                      + pb4.x + pb4.y + pb4.z + pb4.w;
#pragma unroll
            for (int o = 32; o >= 1; o >>= 1) s64 += __shfl_xor(s64, o, 64);
            float l64 = s64 + br64;
            float mx = fmaxf(lj, l64);
#pragma unroll
            for (int o = 32; o >= 1; o >>= 1) mx = fmaxf(mx, __shfl_xor(mx, o, 64));
            float e = __expf(lj - mx);
            float e64 = __expf(l64 - mx);
            float sm = e;
#pragma unroll
            for (int o = 32; o >= 1; o >>= 1) sm += __shfl_xor(sm, o, 64);
            sm += e64;
            lds_rw[wb][jj] = e / sm;
            if (jj == 0) lds_rw[wb][64] = e64 / sm;
        }
        __syncthreads();

        // ---- attended ----
        float att = lds_rw[hb][64] * xv;
#pragma unroll
        for (int q = 0; q < 16; ++q) {
            float4 rv = *(const float4*)&lds_rw[hb][q * 4];  // broadcast
            att += rv.x * memc[q*4+0] + rv.y * memc[q*4+1]
                 + rv.z * memc[q*4+2] + rv.w * memc[q*4+3];
        }
        att_lds[hb][ut] = att;
        __syncthreads();

        // ---- Wt 2-row GEMM (fp16 weights): wave kc owns k in [kc*32,+32) ----
        // lane jj: cols jj*8..jj*8+7 via one half8 (16B) load per k.
        {
            float acc0[8], acc1[8];
#pragma unroll
            for (int c = 0; c < 8; ++c) { acc0[c] = 0.f; acc1[c] = 0.f; }
            const int kbase = kc * 32;
#pragma unroll 4
            for (int k = 0; k < 32; ++k) {
                half8 w = Wt8[(size_t)(kbase + k) * 64 + jj];   // coalesced 1KB/wave
                float a0 = att_lds[0][kbase + k];               // broadcast
                float a1 = att_lds[1][kbase + k];
#pragma unroll
                for (int c = 0; c < 8; ++c) {
                    float wf = (float)w[c];
                    acc0[c] += a0 * wf;
                    acc1[c] += a1 * wf;
                }
            }
            *(float4*)&pWt[kc][0][jj * 8]     = make_float4(acc0[0], acc0[1], acc0[2], acc0[3]);
            *(float4*)&pWt[kc][0][jj * 8 + 4] = make_float4(acc0[4], acc0[5], acc0[6], acc0[7]);
            *(float4*)&pWt[kc][1][jj * 8]     = make_float4(acc1[0], acc1[1], acc1[2], acc1[3]);
            *(float4*)&pWt[kc][1][jj * 8 + 4] = make_float4(acc1[4], acc1[5], acc1[6], acc1[7]);
        }
        __syncthreads();

        // ---- reduce 16 partials, relu, store ----
        {
            float s = 0.f;
#pragma unroll
            for (int q = 0; q < 16; ++q) s += pWt[q][hb][ut];
            float tr = fmaxf(s + btv, 0.f);
            tr_lds[hb][ut] = tr;
            out[(size_t)bb * TT * UU + (size_t)t * UU + ut] = tr;
        }

        // prefetch next x (register only)
        {
            int tn = (t + 1 < TT) ? t + 1 : t;
            xv = x[(size_t)bb * TT * UU + (size_t)tn * UU + ut];
        }
        __syncthreads();   // tr_lds ready for next step's write-GEMM
    }
}

extern "C" void kernel_launch(void* const* d_in, const int* in_sizes, int n_in,
                              void* d_out, int out_size, void* d_ws, size_t ws_size,
                              hipStream_t stream) {
    const float* x    = (const float*)d_in[0];
    const float* mem0 = (const float*)d_in[1];
    const float* Wr   = (const float*)d_in[2];
    const float* br   = (const float*)d_in[3];
    const float* Wt   = (const float*)d_in[4];
    const float* bt   = (const float*)d_in[5];
    const float* Ww   = (const float*)d_in[6];
    const float* bw   = (const float*)d_in[7];
    float* out = (float*)d_out;

    _Float16* w16  = (_Float16*)d_ws;          // [NWT | NWR | NWW]
    _Float16* Wt16 = w16;
    _Float16* Wr16 = w16 + NWT;
    _Float16* Ww16 = w16 + NWT + NWR;

    cvt_kernel<<<dim3(256), dim3(256), 0, stream>>>(Wt, Wr, Ww, w16);
    dnc_kernel<<<dim3(NBLK), dim3(NT), 0, stream>>>(
        x, mem0, Wr, br, bt, bw, Wt16, Wr16, Ww16, out);
}

// Round 9
// 2503.880 us; speedup vs baseline: 12.4731x; 1.2385x over previous
//
#include <hip/hip_runtime.h>
#include <cstddef>

#define BB 256
#define TT 256
#define UU 512
#define MM 64
#define NT 1024
#define NBLK 128   // 2 batches per block

typedef _Float16 h2 __attribute__((ext_vector_type(2)));
typedef unsigned int uint32;

#define NWTP (UU / 2 * UU)   // 131072 packed words (Wt)
#define NWWP (UU / 2 * MM)   // 16384 packed words (Ww)
#define NWR  (UU * 65)       // 33280 halves (Wr)

__device__ __forceinline__ uint32 pkf(float lo, float hi) {
    h2 v; v[0] = (_Float16)lo; v[1] = (_Float16)hi;
    return __builtin_bit_cast(uint32, v);
}
__device__ __forceinline__ h2 toh2(uint32 u) { return __builtin_bit_cast(h2, u); }

// LDS-only barrier: waves' LDS writes visible after it, but global loads
// stay in flight (no vmcnt drain — unlike __syncthreads).
__device__ __forceinline__ void bar() {
    asm volatile("s_waitcnt lgkmcnt(0)" ::: "memory");
    __builtin_amdgcn_s_barrier();
}

// One-time (per call) weight repack into d_ws:
//  Wtp[k2*512 + jj*8 + c] = half2(Wt[2k2][col], Wt[2k2+1][col]),
//     col = c<4 ? jj*4+c : 256+jj*4+(c-4)   (lane jj owns those 8 cols)
//  Wwp[k2*64 + jj]        = half2(Ww[2k2][jj], Ww[2k2+1][jj])
//  Wr16 = fp16 copy of Wr
__global__ void cvt_kernel(const float* __restrict__ Wt,
                           const float* __restrict__ Wr,
                           const float* __restrict__ Ww,
                           uint32* __restrict__ Wtp,
                           uint32* __restrict__ Wwp,
                           _Float16* __restrict__ Wr16) {
    int i = blockIdx.x * blockDim.x + threadIdx.x;
    const int n = NWTP + NWWP + NWR;
    for (; i < n; i += gridDim.x * blockDim.x) {
        if (i < NWTP) {
            int k2 = i >> 9, r = i & 511;
            int jj = r >> 3, c = r & 7;
            int col = (c < 4) ? (jj * 4 + c) : (256 + jj * 4 + (c - 4));
            Wtp[i] = pkf(Wt[(size_t)(2 * k2) * UU + col],
                         Wt[(size_t)(2 * k2 + 1) * UU + col]);
        } else if (i < NWTP + NWWP) {
            int j = i - NWTP;
            int k2 = j >> 6, jj = j & 63;
            Wwp[j] = pkf(Ww[(size_t)(2 * k2) * MM + jj],
                         Ww[(size_t)(2 * k2 + 1) * MM + jj]);
        } else {
            int j = i - NWTP - NWWP;
            Wr16[j] = (_Float16)Wr[j];
        }
    }
}

// One block per PAIR of batch rows (128 blocks x 1024 threads), no grid sync.
// Round-8 topology + (1) lgkmcnt-only barriers so global weight loads span
// phases, (2) v_dot2_f32_f16 for Wt/Ww GEMMs with packed activations,
// (3) conflict-free pWt stores.
__global__ __launch_bounds__(NT, 1) void dnc_kernel(
    const float* __restrict__ x,      // [B,T,U]
    const float* __restrict__ mem0,   // [B, M*U]
    const float* __restrict__ Wr,     // [U, M+1]  (fp32, col-64 only)
    const float* __restrict__ br,     // [M+1]
    const float* __restrict__ bt,     // [U]
    const float* __restrict__ bw,     // [M]
    const uint32* __restrict__ Wtp,   // packed Wt
    const uint32* __restrict__ Wwp,   // packed Ww
    const _Float16* __restrict__ Wr16,// [U][65]
    float* __restrict__ out)          // [B,T,U]
{
    const int tid = threadIdx.x;           // 0..1023
    const int hb  = tid >> 9;              // batch half 0/1 (wave-uniform)
    const int ut  = tid & 511;             // owned column
    const int bb  = (blockIdx.x << 1) + hb;
    const int kc  = tid >> 6;              // wave id 0..15 = k-chunk (32 k)
    const int jj  = tid & 63;              // lane
    const int kb2 = kc * 16;               // first k-pair of this wave

    __shared__ __align__(16) float mean_lds[2][UU];
    __shared__ __align__(16) float pbuf[2][UU];
    __shared__ __align__(16) float pWt[16][2][UU];   // 64 KB k-split partials
    __shared__ __align__(16) float p1[16][2][72];
    __shared__ __align__(16) float p2[16][2][68];
    __shared__ __align__(16) float lds_rw[2][72];
    __shared__ __align__(16) float lds_ww[2][MM];
    __shared__ __align__(16) uint32 att2[2][UU / 2]; // packed half2 attended
    __shared__ __align__(16) uint32 tr2[2][UU / 2];  // packed half2 transformed

    // mem[bb, m, ut] in registers
    float memc[MM];
#pragma unroll
    for (int m = 0; m < MM; ++m)
        memc[m] = mem0[(size_t)bb * (MM * UU) + (size_t)m * UU + ut];

    const float btv  = bt[ut];
    const float wr64 = Wr[(size_t)ut * 65 + 64];
    const float bw_j = bw[jj];
    const float br_j = br[jj];
    const float br64 = br[64];

    float tr_prev = 0.f;                       // own column's transformed(t-1)
    float xv = x[(size_t)bb * TT * UU + ut];   // x[bb,0,ut]

    for (int t = 0; t < TT; ++t) {
        // ---- write weights of t-1 (dot2 GEMM on Wwp), mem update ----
        if (t > 0) {
            {
                float pa = 0.f, pb = 0.f;
                const uint32* wp = Wwp + (size_t)kb2 * 64 + jj;
#pragma unroll 8
                for (int kp = 0; kp < 16; ++kp) {
                    h2 w = toh2(wp[(size_t)kp * 64]);       // coalesced, L2-hit
                    pa = __builtin_amdgcn_fdot2(w, toh2(tr2[0][kb2 + kp]), pa, false);
                    pb = __builtin_amdgcn_fdot2(w, toh2(tr2[1][kb2 + kp]), pb, false);
                }
                p2[kc][0][jj] = pa;
                p2[kc][1][jj] = pb;
            }
            bar();
            if (tid < 128) {
                int wb = tid >> 6;
                float s = bw_j;
#pragma unroll
                for (int q = 0; q < 16; ++q) s += p2[q][wb][jj];
                lds_ww[wb][jj] = 1.f / (1.f + __expf(-s));
            }
            bar();
#pragma unroll
            for (int q = 0; q < 16; ++q) {
                float4 wv = *(const float4*)&lds_ww[hb][q * 4];  // broadcast
                memc[q*4+0] = (1.f - wv.x) * memc[q*4+0] + wv.x * tr_prev;
                memc[q*4+1] = (1.f - wv.y) * memc[q*4+1] + wv.y * tr_prev;
                memc[q*4+2] = (1.f - wv.z) * memc[q*4+2] + wv.z * tr_prev;
                memc[q*4+3] = (1.f - wv.w) * memc[q*4+3] + wv.w * tr_prev;
            }
        }

        // ---- mean over M+1 rows ----
        float colsum = 0.f;
#pragma unroll
        for (int m = 0; m < MM; ++m) colsum += memc[m];
        float meanv = (colsum + xv) * (1.f / 65.f);
        mean_lds[hb][ut] = meanv;
        pbuf[hb][ut] = meanv * wr64;
        bar();

        // ---- read-GEMM: logits partials (cols 0..63), fp16 weights ----
        {
            float pa = 0.f, pb = 0.f;
            const _Float16* wrp = Wr16 + (size_t)(kc * 32) * 65 + jj;
#pragma unroll 8
            for (int k = 0; k < 32; ++k) {
                float w = (float)wrp[(size_t)k * 65];       // coalesced, L2-hit
                pa += mean_lds[0][kc * 32 + k] * w;
                pb += mean_lds[1][kc * 32 + k] * w;
            }
            p1[kc][0][jj] = pa;
            p1[kc][1][jj] = pb;
        }
        bar();

        // ---- softmax over 65: wave 0 -> batch 0, wave 1 -> batch 1 ----
        if (tid < 128) {
            int wb = tid >> 6;
            float lj = br_j;
#pragma unroll
            for (int q = 0; q < 16; ++q) lj += p1[q][wb][jj];
            float4 pa4 = *(const float4*)&pbuf[wb][jj * 8];
            float4 pb4 = *(const float4*)&pbuf[wb][jj * 8 + 4];
            float s64 = pa4.x + pa4.y + pa4.z + pa4.w
                      + pb4.x + pb4.y + pb4.z + pb4.w;
#pragma unroll
            for (int o = 32; o >= 1; o >>= 1) s64 += __shfl_xor(s64, o, 64);
            float l64 = s64 + br64;
            float mx = fmaxf(lj, l64);
#pragma unroll
            for (int o = 32; o >= 1; o >>= 1) mx = fmaxf(mx, __shfl_xor(mx, o, 64));
            float e = __expf(lj - mx);
            float e64 = __expf(l64 - mx);
            float sm = e;
#pragma unroll
            for (int o = 32; o >= 1; o >>= 1) sm += __shfl_xor(sm, o, 64);
            sm += e64;
            lds_rw[wb][jj] = e / sm;
            if (jj == 0) lds_rw[wb][64] = e64 / sm;
        }
        bar();

        // ---- attended + pack to half2 pairs ----
        {
            float att = lds_rw[hb][64] * xv;
#pragma unroll
            for (int q = 0; q < 16; ++q) {
                float4 rv = *(const float4*)&lds_rw[hb][q * 4];  // broadcast
                att += rv.x * memc[q*4+0] + rv.y * memc[q*4+1]
                     + rv.z * memc[q*4+2] + rv.w * memc[q*4+3];
            }
            float attn = __shfl_down(att, 1, 64);
            if ((ut & 1) == 0) att2[hb][ut >> 1] = pkf(att, attn);
        }
        bar();

        // ---- Wt dot2-GEMM: wave kc owns k-pairs [kb2, kb2+16) ----
        // lane jj: cols {jj*4..+3, 256+jj*4..+3}; 32B load + 16 dot2 per kp.
        {
            float acc0[8], acc1[8];
#pragma unroll
            for (int c = 0; c < 8; ++c) { acc0[c] = 0.f; acc1[c] = 0.f; }
            const uint4* Wp = (const uint4*)Wtp + (size_t)kb2 * 128 + jj * 2;
#pragma unroll 4
            for (int kp = 0; kp < 16; ++kp) {
                uint4 L = Wp[(size_t)kp * 128];       // coalesced 2KB/wave
                uint4 H = Wp[(size_t)kp * 128 + 1];
                h2 a0 = toh2(att2[0][kb2 + kp]);      // broadcast
                h2 a1 = toh2(att2[1][kb2 + kp]);
                acc0[0] = __builtin_amdgcn_fdot2(toh2(L.x), a0, acc0[0], false);
                acc0[1] = __builtin_amdgcn_fdot2(toh2(L.y), a0, acc0[1], false);
                acc0[2] = __builtin_amdgcn_fdot2(toh2(L.z), a0, acc0[2], false);
                acc0[3] = __builtin_amdgcn_fdot2(toh2(L.w), a0, acc0[3], false);
                acc0[4] = __builtin_amdgcn_fdot2(toh2(H.x), a0, acc0[4], false);
                acc0[5] = __builtin_amdgcn_fdot2(toh2(H.y), a0, acc0[5], false);
                acc0[6] = __builtin_amdgcn_fdot2(toh2(H.z), a0, acc0[6], false);
                acc0[7] = __builtin_amdgcn_fdot2(toh2(H.w), a0, acc0[7], false);
                acc1[0] = __builtin_amdgcn_fdot2(toh2(L.x), a1, acc1[0], false);
                acc1[1] = __builtin_amdgcn_fdot2(toh2(L.y), a1, acc1[1], false);
                acc1[2] = __builtin_amdgcn_fdot2(toh2(L.z), a1, acc1[2], false);
                acc1[3] = __builtin_amdgcn_fdot2(toh2(L.w), a1, acc1[3], false);
                acc1[4] = __builtin_amdgcn_fdot2(toh2(H.x), a1, acc1[4], false);
                acc1[5] = __builtin_amdgcn_fdot2(toh2(H.y), a1, acc1[5], false);
                acc1[6] = __builtin_amdgcn_fdot2(toh2(H.z), a1, acc1[6], false);
                acc1[7] = __builtin_amdgcn_fdot2(toh2(H.w), a1, acc1[7], false);
            }
            // conflict-free stores: lane-consecutive float4s
            *(float4*)&pWt[kc][0][jj * 4]       = make_float4(acc0[0], acc0[1], acc0[2], acc0[3]);
            *(float4*)&pWt[kc][0][256 + jj * 4] = make_float4(acc0[4], acc0[5], acc0[6], acc0[7]);
            *(float4*)&pWt[kc][1][jj * 4]       = make_float4(acc1[0], acc1[1], acc1[2], acc1[3]);
            *(float4*)&pWt[kc][1][256 + jj * 4] = make_float4(acc1[4], acc1[5], acc1[6], acc1[7]);
        }
        bar();

        // ---- reduce 16 partials, relu, store, pack tr pairs ----
        {
            float s = 0.f;
#pragma unroll
            for (int q = 0; q < 16; ++q) s += pWt[q][hb][ut];
            float tr = fmaxf(s + btv, 0.f);
            tr_prev = tr;
            out[(size_t)bb * TT * UU + (size_t)t * UU + ut] = tr;
            float trn = __shfl_down(tr, 1, 64);
            if ((ut & 1) == 0) tr2[hb][ut >> 1] = pkf(tr, trn);
        }

        // prefetch next x (register only)
        {
            int tn = (t + 1 < TT) ? t + 1 : t;
            xv = x[(size_t)bb * TT * UU + (size_t)tn * UU + ut];
        }
        bar();   // tr2 visible for next step's write-GEMM
    }
}

extern "C" void kernel_launch(void* const* d_in, const int* in_sizes, int n_in,
                              void* d_out, int out_size, void* d_ws, size_t ws_size,
                              hipStream_t stream) {
    const float* x    = (const float*)d_in[0];
    const float* mem0 = (const float*)d_in[1];
    const float* Wr   = (const float*)d_in[2];
    const float* br   = (const float*)d_in[3];
    const float* Wt   = (const float*)d_in[4];
    const float* bt   = (const float*)d_in[5];
    const float* Ww   = (const float*)d_in[6];
    const float* bw   = (const float*)d_in[7];
    float* out = (float*)d_out;

    uint32*   Wtp  = (uint32*)d_ws;                 // [NWTP]
    uint32*   Wwp  = Wtp + NWTP;                    // [NWWP]
    _Float16* Wr16 = (_Float16*)(Wwp + NWWP);       // [NWR]

    cvt_kernel<<<dim3(256), dim3(256), 0, stream>>>(Wt, Wr, Ww, Wtp, Wwp, Wr16);
    dnc_kernel<<<dim3(NBLK), dim3(NT), 0, stream>>>(
        x, mem0, Wr, br, bt, bw, Wtp, Wwp, Wr16, out);
}

// Round 10
// 1689.908 us; speedup vs baseline: 18.4810x; 1.4817x over previous
//
#include <hip/hip_runtime.h>
#include <cstddef>

#define BB 256
#define TT 256
#define UU 512
#define MM 64
#define NT 512

typedef _Float16 h2 __attribute__((ext_vector_type(2)));
typedef unsigned int uint32;

#define NWTP (UU / 2 * UU)   // 131072 packed words (Wt)
#define NWWP (UU / 2 * MM)   // 16384 packed words (Ww)
#define NWRP (UU / 2 * MM)   // 16384 packed words (Wr cols 0..63)

__device__ __forceinline__ uint32 pkf(float lo, float hi) {
    h2 v; v[0] = (_Float16)lo; v[1] = (_Float16)hi;
    return __builtin_bit_cast(uint32, v);
}
__device__ __forceinline__ h2 toh2(uint32 u) { return __builtin_bit_cast(h2, u); }

// LDS-only barrier: LDS writes visible, global loads stay in flight.
__device__ __forceinline__ void bar() {
    asm volatile("s_waitcnt lgkmcnt(0)" ::: "memory");
    __builtin_amdgcn_s_barrier();
}

// One-time weight repack into d_ws:
//  Wtp[k2*512 + jj*8 + c] = half2(Wt[2k2][col], Wt[2k2+1][col]),
//     col = c<4 ? jj*4+c : 256+jj*4+(c-4)
//  Wwp[k2*64 + jj] = half2(Ww[2k2][jj], Ww[2k2+1][jj])
//  Wrp[k2*64 + jj] = half2(Wr[2k2][jj], Wr[2k2+1][jj])   (cols 0..63)
__global__ void cvt_kernel(const float* __restrict__ Wt,
                           const float* __restrict__ Wr,
                           const float* __restrict__ Ww,
                           uint32* __restrict__ Wtp,
                           uint32* __restrict__ Wwp,
                           uint32* __restrict__ Wrp) {
    int i = blockIdx.x * blockDim.x + threadIdx.x;
    const int n = NWTP + NWWP + NWRP;
    for (; i < n; i += gridDim.x * blockDim.x) {
        if (i < NWTP) {
            int k2 = i >> 9, r = i & 511;
            int jj = r >> 3, c = r & 7;
            int col = (c < 4) ? (jj * 4 + c) : (256 + jj * 4 + (c - 4));
            Wtp[i] = pkf(Wt[(size_t)(2 * k2) * UU + col],
                         Wt[(size_t)(2 * k2 + 1) * UU + col]);
        } else if (i < NWTP + NWWP) {
            int j = i - NWTP;
            int k2 = j >> 6, jj = j & 63;
            Wwp[j] = pkf(Ww[(size_t)(2 * k2) * MM + jj],
                         Ww[(size_t)(2 * k2 + 1) * MM + jj]);
        } else {
            int j = i - NWTP - NWWP;
            int k2 = j >> 6, jj = j & 63;
            Wrp[j] = pkf(Wr[(size_t)(2 * k2) * 65 + jj],
                         Wr[(size_t)(2 * k2 + 1) * 65 + jj]);
        }
    }
}

// 256 blocks x 512 threads, 1 batch/block, no grid sync.
// Half of Wt lives in registers PERMANENTLY (t-invariant addresses):
// wave w caches k-pairs [w*32, w*32+16) (32 uint4 = 128 VGPR), streams the
// other 16 kp + Wr + Ww from L2. memc[64] holds mem[b,:,ut]. All GEMVs use
// v_dot2_f32_f16 with packed fp16 activations (r9-validated numerics).
__global__ __launch_bounds__(NT, 1) void dnc_kernel(
    const float* __restrict__ x,      // [B,T,U]
    const float* __restrict__ mem0,   // [B, M*U]
    const float* __restrict__ Wr,     // [U, M+1]  (fp32, col-64 only)
    const float* __restrict__ br,     // [M+1]
    const float* __restrict__ bt,     // [U]
    const float* __restrict__ bw,     // [M]
    const uint32* __restrict__ Wtp,
    const uint32* __restrict__ Wwp,
    const uint32* __restrict__ Wrp,
    float* __restrict__ out)          // [B,T,U]
{
    const int tid = threadIdx.x;   // 0..511
    const int b   = blockIdx.x;
    const int w   = tid >> 6;      // wave 0..7 (k-chunk, 32 k-pairs each)
    const int jj  = tid & 63;      // lane
    const int ut  = tid;           // owned output column

    __shared__ __align__(16) float  pWt[8][UU];     // 16 KB k-split partials
    __shared__ __align__(16) float  p1[8][68];
    __shared__ __align__(16) float  p2[8][68];
    __shared__ __align__(16) float  pbuf[UU];
    __shared__ __align__(16) float  lds_rw[72];
    __shared__ __align__(16) float  lds_ww[MM];
    __shared__ __align__(16) uint32 mean2[UU / 2];
    __shared__ __align__(16) uint32 att2[UU / 2];
    __shared__ __align__(16) uint32 tr2[UU / 2];

    const uint4* Wp4 = (const uint4*)Wtp;   // [k2][128] uint4 pairs

    // ---- permanent register cache: Wt k-pairs [w*32, w*32+16) ----
    uint4 wtcL[16], wtcH[16];
#pragma unroll
    for (int i = 0; i < 16; ++i) {
        size_t base = (size_t)(w * 32 + i) * 128 + jj * 2;
        wtcL[i] = Wp4[base];
        wtcH[i] = Wp4[base + 1];
    }

    float memc[MM];
#pragma unroll
    for (int m = 0; m < MM; ++m)
        memc[m] = mem0[(size_t)b * (MM * UU) + (size_t)m * UU + ut];

    const float btv  = bt[ut];
    const float wr64 = Wr[(size_t)ut * 65 + 64];
    const float bw_j = bw[jj];
    const float br_j = br[jj];
    const float br64 = br[64];

    float tr_prev = 0.f;
    float xv = x[(size_t)b * TT * UU + ut];

    for (int t = 0; t < TT; ++t) {
        // ---- write weights of t-1 (Ww stream), mem update ----
        if (t > 0) {
            {
                float pa = 0.f;
                const uint32* wp = Wwp + (size_t)(w * 32) * 64 + jj;
#pragma unroll 8
                for (int kp = 0; kp < 32; ++kp)
                    pa = __builtin_amdgcn_fdot2(toh2(wp[(size_t)kp * 64]),
                                                toh2(tr2[w * 32 + kp]), pa, false);
                p2[w][jj] = pa;
            }
            bar();
            if (tid < 64) {
                float s = bw_j;
#pragma unroll
                for (int q = 0; q < 8; ++q) s += p2[q][tid];
                lds_ww[tid] = 1.f / (1.f + __expf(-s));
            }
            bar();
#pragma unroll
            for (int q = 0; q < 16; ++q) {
                float4 wv = *(const float4*)&lds_ww[q * 4];   // broadcast
                memc[q*4+0] = (1.f - wv.x) * memc[q*4+0] + wv.x * tr_prev;
                memc[q*4+1] = (1.f - wv.y) * memc[q*4+1] + wv.y * tr_prev;
                memc[q*4+2] = (1.f - wv.z) * memc[q*4+2] + wv.z * tr_prev;
                memc[q*4+3] = (1.f - wv.w) * memc[q*4+3] + wv.w * tr_prev;
            }
        }

        // ---- mean over M+1 rows, pack to h2 ----
        {
            float colsum = 0.f;
#pragma unroll
            for (int m = 0; m < MM; ++m) colsum += memc[m];
            float meanv = (colsum + xv) * (1.f / 65.f);
            pbuf[ut] = meanv * wr64;
            float mn = __shfl_down(meanv, 1, 64);
            if ((ut & 1) == 0) mean2[ut >> 1] = pkf(meanv, mn);
        }
        bar();

        // ---- read-GEMV: logits partials (cols 0..63), Wr stream ----
        {
            float pr = 0.f;
            const uint32* wrp = Wrp + (size_t)(w * 32) * 64 + jj;
#pragma unroll 8
            for (int kp = 0; kp < 32; ++kp)
                pr = __builtin_amdgcn_fdot2(toh2(wrp[(size_t)kp * 64]),
                                            toh2(mean2[w * 32 + kp]), pr, false);
            p1[w][jj] = pr;
        }
        bar();

        // ---- softmax over 65 on wave 0 ----
        if (tid < 64) {
            float lj = br_j;
#pragma unroll
            for (int q = 0; q < 8; ++q) lj += p1[q][tid];
            float4 pa4 = *(const float4*)&pbuf[tid * 8];
            float4 pb4 = *(const float4*)&pbuf[tid * 8 + 4];
            float s64 = pa4.x + pa4.y + pa4.z + pa4.w
                      + pb4.x + pb4.y + pb4.z + pb4.w;
#pragma unroll
            for (int o = 32; o >= 1; o >>= 1) s64 += __shfl_xor(s64, o, 64);
            float l64 = s64 + br64;
            float mx = fmaxf(lj, l64);
#pragma unroll
            for (int o = 32; o >= 1; o >>= 1) mx = fmaxf(mx, __shfl_xor(mx, o, 64));
            float e = __expf(lj - mx);
            float e64 = __expf(l64 - mx);
            float sm = e;
#pragma unroll
            for (int o = 32; o >= 1; o >>= 1) sm += __shfl_xor(sm, o, 64);
            sm += e64;
            lds_rw[tid] = e / sm;
            if (tid == 0) lds_rw[64] = e64 / sm;
        }
        bar();

        // ---- attended (fp32), pack to h2 ----
        {
            float att = lds_rw[64] * xv;
#pragma unroll
            for (int q = 0; q < 16; ++q) {
                float4 rv = *(const float4*)&lds_rw[q * 4];   // broadcast
                att += rv.x * memc[q*4+0] + rv.y * memc[q*4+1]
                     + rv.z * memc[q*4+2] + rv.w * memc[q*4+3];
            }
            float an = __shfl_down(att, 1, 64);
            if ((ut & 1) == 0) att2[ut >> 1] = pkf(att, an);
        }
        bar();

        // ---- Wt GEMV: 16 cached kp (registers) + 16 streamed kp ----
        {
            float acc[8];
#pragma unroll
            for (int c = 0; c < 8; ++c) acc[c] = 0.f;

            // streamed half first: issue loads early, consume pipelined
            const uint4* sp = Wp4 + (size_t)(w * 32 + 16) * 128 + jj * 2;
#pragma unroll 4
            for (int i = 0; i < 16; ++i) {
                uint4 L = sp[(size_t)i * 128];
                uint4 H = sp[(size_t)i * 128 + 1];
                h2 a = toh2(att2[w * 32 + 16 + i]);           // broadcast
                acc[0] = __builtin_amdgcn_fdot2(toh2(L.x), a, acc[0], false);
                acc[1] = __builtin_amdgcn_fdot2(toh2(L.y), a, acc[1], false);
                acc[2] = __builtin_amdgcn_fdot2(toh2(L.z), a, acc[2], false);
                acc[3] = __builtin_amdgcn_fdot2(toh2(L.w), a, acc[3], false);
                acc[4] = __builtin_amdgcn_fdot2(toh2(H.x), a, acc[4], false);
                acc[5] = __builtin_amdgcn_fdot2(toh2(H.y), a, acc[5], false);
                acc[6] = __builtin_amdgcn_fdot2(toh2(H.z), a, acc[6], false);
                acc[7] = __builtin_amdgcn_fdot2(toh2(H.w), a, acc[7], false);
            }
            // cached half: pure register dot2s
#pragma unroll
            for (int i = 0; i < 16; ++i) {
                h2 a = toh2(att2[w * 32 + i]);                // broadcast
                acc[0] = __builtin_amdgcn_fdot2(toh2(wtcL[i].x), a, acc[0], false);
                acc[1] = __builtin_amdgcn_fdot2(toh2(wtcL[i].y), a, acc[1], false);
                acc[2] = __builtin_amdgcn_fdot2(toh2(wtcL[i].z), a, acc[2], false);
                acc[3] = __builtin_amdgcn_fdot2(toh2(wtcL[i].w), a, acc[3], false);
                acc[4] = __builtin_amdgcn_fdot2(toh2(wtcH[i].x), a, acc[4], false);
                acc[5] = __builtin_amdgcn_fdot2(toh2(wtcH[i].y), a, acc[5], false);
                acc[6] = __builtin_amdgcn_fdot2(toh2(wtcH[i].z), a, acc[6], false);
                acc[7] = __builtin_amdgcn_fdot2(toh2(wtcH[i].w), a, acc[7], false);
            }
            *(float4*)&pWt[w][jj * 4]       = make_float4(acc[0], acc[1], acc[2], acc[3]);
            *(float4*)&pWt[w][256 + jj * 4] = make_float4(acc[4], acc[5], acc[6], acc[7]);
        }
        bar();

        // ---- reduce 8 partials, relu, store, pack tr2 ----
        {
            float s = 0.f;
#pragma unroll
            for (int q = 0; q < 8; ++q) s += pWt[q][ut];
            float tr = fmaxf(s + btv, 0.f);
            tr_prev = tr;
            out[(size_t)b * TT * UU + (size_t)t * UU + ut] = tr;
            float trn = __shfl_down(tr, 1, 64);
            if ((ut & 1) == 0) tr2[ut >> 1] = pkf(tr, trn);
        }

        // prefetch next x (register only)
        {
            int tn = (t + 1 < TT) ? t + 1 : t;
            xv = x[(size_t)b * TT * UU + (size_t)tn * UU + ut];
        }
        bar();   // tr2 visible for next step's write-GEMV
    }
}

extern "C" void kernel_launch(void* const* d_in, const int* in_sizes, int n_in,
                              void* d_out, int out_size, void* d_ws, size_t ws_size,
                              hipStream_t stream) {
    const float* x    = (const float*)d_in[0];
    const float* mem0 = (const float*)d_in[1];
    const float* Wr   = (const float*)d_in[2];
    const float* br   = (const float*)d_in[3];
    const float* Wt   = (const float*)d_in[4];
    const float* bt   = (const float*)d_in[5];
    const float* Ww   = (const float*)d_in[6];
    const float* bw   = (const float*)d_in[7];
    float* out = (float*)d_out;

    uint32* Wtp = (uint32*)d_ws;          // [NWTP]
    uint32* Wwp = Wtp + NWTP;             // [NWWP]
    uint32* Wrp = Wwp + NWWP;             // [NWRP]

    cvt_kernel<<<dim3(256), dim3(256), 0, stream>>>(Wt, Wr, Ww, Wtp, Wwp, Wrp);
    dnc_kernel<<<dim3(BB), dim3(NT), 0, stream>>>(
        x, mem0, Wr, br, bt, bw, Wtp, Wwp, Wrp, out);
}